// Round 6
// baseline (136.186 us; speedup 1.0000x reference)
//
#include <hip/hip_runtime.h>
#include <hip/hip_fp16.h>
#include <cstdint>
#include <cstddef>

// Problem constants
#define B_ 16
#define K_ 49
#define T_ 256
#define H_ 512
#define D_ 512

// tanh(x) = 1 - 2/(1 + e^{2x}) = 1 - 2*rcp(1 + 2^{x*2*log2e})
// TANH_SCALE folded into Wv/Wg/Ws (+biases); gemm epilogue stores 2^(scaled dot),
// so z_kernel's inner loop is pure fma/rcp (zero transcendentals).
#define TANH_SCALE 2.8853900817779268f
#define LOG2E 1.4426950408889634f

typedef _Float16 half8 __attribute__((ext_vector_type(8)));
typedef float floatx4 __attribute__((ext_vector_type(4)));

// A matrix (fp16) rows: [0,784)=V, [784,896)=pad0, [896,4992)=h_t, [4992,9088)=s_t
#define ROWS_A 9088
#define OFF_V 0
#define OFF_H 896
#define OFF_S 4992

__device__ __forceinline__ void async16(const _Float16* g, const _Float16* l) {
    // width=16 global->LDS DMA; LDS dest = wave-uniform base + lane*16
    __builtin_amdgcn_global_load_lds(
        (const __attribute__((address_space(1))) unsigned int*)g,
        (__attribute__((address_space(3))) unsigned int*)l, 16, 0, 0);
}

// ---------------- merged conversion kernel (unchanged) ----------------
__global__ __launch_bounds__(256) void conv_all(const float* __restrict__ V,
                                                const float* __restrict__ h_t,
                                                const float* __restrict__ s_t,
                                                const float* __restrict__ Wv,
                                                const float* __restrict__ Wg,
                                                const float* __restrict__ Ws,
                                                _Float16* __restrict__ Af16,
                                                _Float16* __restrict__ Wt) {
    __shared__ float tile[32][33];
    int tid = threadIdx.x;
    if (blockIdx.x < 2272) {
        int idx = (blockIdx.x * 256 + tid) * 8;
        int row = idx >> 9;
        int col = idx & 511;
        const float* src;
        if (row < 784)        src = V   + (size_t)row * 512 + col;
        else if (row < 896)   src = nullptr;
        else if (row < 4992)  src = h_t + (size_t)(row - 896) * 512 + col;
        else                  src = s_t + (size_t)(row - 4992) * 512 + col;
        half8 h;
        if (src) {
            float4 f0 = *(const float4*)(src);
            float4 f1 = *(const float4*)(src + 4);
            h[0] = (_Float16)f0.x; h[1] = (_Float16)f0.y;
            h[2] = (_Float16)f0.z; h[3] = (_Float16)f0.w;
            h[4] = (_Float16)f1.x; h[5] = (_Float16)f1.y;
            h[6] = (_Float16)f1.z; h[7] = (_Float16)f1.w;
        } else {
            h = (half8)((_Float16)0.0f);
        }
        *(half8*)(Af16 + idx) = h;
    } else {
        int bid = blockIdx.x - 2272;
        int p = bid >> 8;
        int rem = bid & 255;
        int bx = rem & 15, by = rem >> 4;
        const float* W = (p == 0) ? Wv : (p == 1) ? Wg : Ws;
        _Float16* outp = Wt + (size_t)p * 512 * 512;
        int tx = tid & 31, ty = tid >> 5;
        int c = bx * 32 + tx;
        int rbase = by * 32;
#pragma unroll
        for (int i = 0; i < 4; i++)
            tile[ty + i * 8][tx] = W[(size_t)(rbase + ty + i * 8) * 512 + c];
        __syncthreads();
        int k = rbase + tx;
#pragma unroll
        for (int i = 0; i < 4; i++) {
            int n = bx * 32 + ty + i * 8;
            outp[(size_t)n * 512 + k] = (_Float16)(tile[tx][ty + i * 8] * TANH_SCALE);
        }
    }
}

// ---------------- 3-problem fp16 MFMA GEMM, 128x128 tiles, BK=128, 2-buffer ----------------
// C = 2^(A @ W^T + bias)  (exp2 applied in epilogue: z_kernel consumes only 2^x).
// Rounds 0-5 post-mortem: every LDS schedule (drain, issue-early, counted depth-2,
// 64^2 or 128^2/BK=32) lands at 25-28 us because the cost is PER K-STEP SLOT
// (~2-4k cyc of staging round-trip + barriers + LDS DMA), and we were paying it
// 8-16 times. Fix: BK=128 -> only 4 slots, each carrying 64 MFMAs/wave.
// 2x64KB double-buffered LDS (128 KiB total; m201-template precedent for plain-HIP
// static LDS of this size on gfx950). Counted vmcnt(16): while computing step kk,
// the 16 DMA loads of step kk+1 fly under the ~2k-cyc compute phase.
// Per-iter sequence: barrier1 (readers of buf[cur^1] done; WAR-safe) ->
// issue stage(kk+1) into buf[cur^1] -> s_waitcnt vmcnt(16) (retires stage(kk);
// per-wave, so barrier2 makes all waves' chunks visible) -> barrier2 -> compute.
// Fragment-order LDS per buffer: chunk c = ks*512 + x8*64 + (lane) holds
// row = x8*16 + (c&15), k-cols = kk*128 + ks*32 + ((c>>4)&3)*8 .. +8 ; frag read
// addr (ks*512 + x8*64 + lane)*8 -> conflict-free ds_read_b128 (verified layout).
// XCD swizzle, bijective over 284 = 4*36 + 4*35 (ERRATA #11 form).
__global__ __launch_bounds__(256) void gemm_f16(
    const _Float16* __restrict__ Af16, const _Float16* __restrict__ Wt,
    const float* __restrict__ bv, const float* __restrict__ bg2,
    const float* __restrict__ bs, float* __restrict__ cv,
    float* __restrict__ cg, float* __restrict__ cs) {
    __shared__ __align__(16) _Float16 As[2][128 * 128];   // 2 x 32 KB
    __shared__ __align__(16) _Float16 Bs[2][128 * 128];   // 2 x 32 KB  (128 KB total)

    int bid = blockIdx.x;
    int jj = bid >> 3, xcd = bid & 7;
    int id = (xcd < 4) ? xcd * 36 + jj : 144 + (xcd - 4) * 35 + jj;   // bijective 284

    int rowbase; const _Float16* Bt; const float* bias; float* C;
    if (id < 28)        {            rowbase = OFF_V; Bt = Wt;          bias = bv;  C = cv; }
    else if (id < 156)  { id -= 28;  rowbase = OFF_H; Bt = Wt + 262144; bias = bg2; C = cg; }
    else                { id -= 156; rowbase = OFF_S; Bt = Wt + 524288; bias = bs;  C = cs; }
    int mrel = (id >> 2) * 128;          // output row base within this problem
    int m0 = rowbase + mrel;             // row base in Af16
    int n0 = (id & 3) * 128;             // output col base

    int tid = threadIdx.x;
    int wave = tid >> 6, lane = tid & 63;
    int wr = wave >> 1, wc = wave & 1;   // 2x2 wave grid, each wave 64x64 out

    // staging chunk c = i*256 + tid (0..2047): ks=c>>9, x8=(c>>6)&7, q=(c>>4)&3, f=c&15
    // LDS elem offset = c*8 ; global row = base + x8*16 + f, elem col = kk*128 + ks*32 + q*8
    const _Float16* gA[8]; const _Float16* gB[8]; int ldsOff[8];
#pragma unroll
    for (int i = 0; i < 8; i++) {
        int c = i * 256 + tid;
        int ks = c >> 9, x8 = (c >> 6) & 7, q = (c >> 4) & 3, f = c & 15;
        gA[i] = Af16 + (size_t)(m0 + x8 * 16 + f) * 512 + ks * 32 + q * 8;
        gB[i] = Bt   + (size_t)(n0 + x8 * 16 + f) * 512 + ks * 32 + q * 8;
        ldsOff[i] = c * 8;
    }

    floatx4 acc[4][4];
#pragma unroll
    for (int x = 0; x < 4; x++)
#pragma unroll
        for (int y = 0; y < 4; y++) acc[x][y] = (floatx4)0.0f;

    // prologue: stage K-step 0 into buffer 0 (16 loads in flight per thread)
#pragma unroll
    for (int i = 0; i < 8; i++) async16(gA[i], &As[0][ldsOff[i]]);
#pragma unroll
    for (int i = 0; i < 8; i++) async16(gB[i], &Bs[0][ldsOff[i]]);

#pragma unroll
    for (int kk = 0; kk < 4; kk++) {
        const int cur = kk & 1;
        __builtin_amdgcn_s_barrier();          // all readers of buf[cur^1] done (WAR)
        __builtin_amdgcn_sched_barrier(0);
        if (kk < 3) {
#pragma unroll
            for (int i = 0; i < 8; i++) async16(gA[i] + (kk + 1) * 128, &As[cur ^ 1][ldsOff[i]]);
#pragma unroll
            for (int i = 0; i < 8; i++) async16(gB[i] + (kk + 1) * 128, &Bs[cur ^ 1][ldsOff[i]]);
            asm volatile("s_waitcnt vmcnt(16)" ::: "memory");   // stage(kk) landed
        } else {
            asm volatile("s_waitcnt vmcnt(0)" ::: "memory");    // last step: drain
        }
        __builtin_amdgcn_s_barrier();          // buf[cur] visible from all waves
        __builtin_amdgcn_sched_barrier(0);

#pragma unroll
        for (int ks = 0; ks < 4; ks++) {
            half8 a[4], b[4];
#pragma unroll
            for (int t = 0; t < 4; t++) {
                a[t] = *(const half8*)&As[cur][(ks * 512 + (wr * 4 + t) * 64 + lane) * 8];
                b[t] = *(const half8*)&Bs[cur][(ks * 512 + (wc * 4 + t) * 64 + lane) * 8];
            }
#pragma unroll
            for (int x = 0; x < 4; x++)
#pragma unroll
                for (int y = 0; y < 4; y++)
                    acc[x][y] = __builtin_amdgcn_mfma_f32_16x16x32_f16(a[x], b[y], acc[x][y], 0, 0, 0);
        }
    }

    // epilogue: C/D layout col=lane&15, row=(lane>>4)*4+reg ; store 2^(dot+bias)
    int dn = lane & 15, dq = lane >> 4;
#pragma unroll
    for (int y = 0; y < 4; y++) {
        int colg = n0 + wc * 64 + y * 16 + dn;
        float bc = bias[colg] * TANH_SCALE;
#pragma unroll
        for (int x = 0; x < 4; x++) {
            int rowg = mrel + wr * 64 + x * 16 + dq * 4;
#pragma unroll
            for (int r = 0; r < 4; r++)
                C[(size_t)(rowg + r) * 512 + colg] = __builtin_amdgcn_exp2f(acc[x][y][r] + bc);
        }
    }
}

// ---------------- fused z / softmax / c_t / gate kernel ----------------
__device__ __forceinline__ float wave_sum(float v) {
#pragma unroll
    for (int o = 32; o > 0; o >>= 1) v += __shfl_xor(v, o);
    return v;
}
__device__ __forceinline__ float wave_max(float v) {
#pragma unroll
    for (int o = 32; o > 0; o >>= 1) v = fmaxf(v, __shfl_xor(v, o));
    return v;
}

// Sum 4 independent values across 64 lanes (group g=lane>>4 holds acc_g's total).
__device__ __forceinline__ float xsum4(float a0, float a1, float a2, float a3, int lane) {
    bool hi = (lane & 32) != 0;
    float t0 = hi ? a0 : a2;
    float t1 = hi ? a1 : a3;
    t0 = __shfl_xor(t0, 32);
    t1 = __shfl_xor(t1, 32);
    if (hi) { a0 = t0; a1 = t1; } else { a2 = t0; a3 = t1; }
    bool h2 = (lane & 16) != 0;
    float u0 = h2 ? a0 : a1;
    float u1 = h2 ? a2 : a3;
    u0 = __shfl_xor(u0, 16);
    u1 = __shfl_xor(u1, 16);
    if (h2) { a0 = u0; a2 = u1; } else { a1 = u0; a3 = u1; }
    float s = (a0 + a1) + (a2 + a3);
#pragma unroll
    for (int o = 8; o > 0; o >>= 1) s += __shfl_xor(s, o);
    return s;
}

// ecv/ecg/ecs hold 2^(scaled dot): e = ecv*ecg, tanh-dot = zbase - 2*sum(Wh*rcp(1+e))
#define TB 4
__global__ __launch_bounds__(256) void z_kernel(
    const float* __restrict__ ecv, const float* __restrict__ ecg,
    const float* __restrict__ ecs, const float* __restrict__ V,
    const float* __restrict__ s_t, const float* __restrict__ Wh,
    const float* __restrict__ bh, float* __restrict__ out) {
    int bx = blockIdx.x;           // 1024 blocks: b*64 + tgroup
    int b  = bx >> 6;
    int t0 = (bx & 63) << 2;
    int bt0 = b * 256 + t0;
    int tid = threadIdx.x;
    int wave = tid >> 6, lane = tid & 63;

    __shared__ float zl[TB][64];
    __shared__ float4 al4[52];
    __shared__ float bl[TB];

    // register-resident Wh and egv = 2^cg (d = j*64 + lane fixed per lane)
    float whv[8], egv[TB][8];
#pragma unroll
    for (int j = 0; j < 8; j++) whv[j] = Wh[j * 64 + lane];
#pragma unroll
    for (int tt = 0; tt < TB; tt++) {
        const float* cgp = ecg + (size_t)(bt0 + tt) * 512;
#pragma unroll
        for (int j = 0; j < 8; j++) egv[tt][j] = cgp[j * 64 + lane];
    }
    float s8 = 0.0f;
#pragma unroll
    for (int j = 0; j < 8; j++) s8 += whv[j];
    float zbase = wave_sum(s8) + bh[0];   // sum(Wh)+bh: tanh = 1-2r folded

    // 49 content tasks round-robin over 4 waves, software-prefetched
    float rv[8], rn[8];
    {
        const float* rp = ecv + (size_t)(b * 49 + wave) * 512;
#pragma unroll
        for (int j = 0; j < 8; j++) rv[j] = rp[j * 64 + lane];
    }
    for (int task = wave; task < 49; task += 4) {
        int nt = task + 4;
        if (nt < 49) {
            const float* rp = ecv + (size_t)(b * 49 + nt) * 512;
#pragma unroll
            for (int j = 0; j < 8; j++) rn[j] = rp[j * 64 + lane];
        }
        float acc[TB] = {0.0f, 0.0f, 0.0f, 0.0f};
#pragma unroll
        for (int tt = 0; tt < TB; tt++) {
#pragma unroll
            for (int j = 0; j < 8; j++) {
                float t = fmaf(rv[j], egv[tt][j], 1.0f);       // 1 + 2^(cv+cg)
                float r = __builtin_amdgcn_rcpf(t);            // v_rcp_f32
                acc[tt] = fmaf(whv[j], r, acc[tt]);
            }
        }
        float z = xsum4(acc[0], acc[1], acc[2], acc[3], lane);
        if ((lane & 15) == 0) zl[lane >> 4][task] = zbase - 2.0f * z;
#pragma unroll
        for (int j = 0; j < 8; j++) rv[j] = rn[j];
    }
    // ext task: wave tt handles t0+tt (reuses egv[tt])
#pragma unroll
    for (int tt = 0; tt < TB; tt++) {
        if (wave == tt) {
            const float* rp = ecs + (size_t)(bt0 + tt) * 512;
            float acc = 0.0f;
#pragma unroll
            for (int j = 0; j < 8; j++) {
                float t = fmaf(rp[j * 64 + lane], egv[tt][j], 1.0f);
                float r = __builtin_amdgcn_rcpf(t);
                acc = fmaf(whv[j], r, acc);
            }
            float s = wave_sum(acc);
            if (lane == 0) zl[tt][49] = zbase - 2.0f * s;
        }
    }
    __syncthreads();

    // 4 softmaxes in parallel: wave w handles tt=w
    {
        int w = wave;
        float z = (lane < 49) ? zl[w][lane] : -3.0e38f;
        float m = wave_max(z);
        float e = (lane < 49) ? __builtin_amdgcn_exp2f((z - m) * LOG2E) : 0.0f;
        float s = wave_sum(e);
        float zext = zl[w][49];
        float m2 = fmaxf(m, zext);
        float sc   = __builtin_amdgcn_exp2f((m - m2) * LOG2E);
        float eext = __builtin_amdgcn_exp2f((zext - m2) * LOG2E);
        float s2 = s * sc + eext;
        float beta = eext / s2;
        if (lane < 49) {
            float a = e / s;
            ((float*)&al4[lane])[w] = a;
            out[(size_t)B_ * T_ * H_ + (size_t)(bt0 + w) * 49 + lane] = a;   // alpha_t
        }
        if (lane == 0) {
            bl[w] = beta;
            out[(size_t)B_ * T_ * H_ + (size_t)B_ * T_ * K_ + (bt0 + w)] = beta;  // beta_t
        }
    }
    __syncthreads();

    // c_t + gate: float2 per lane, V read once per block
    const float* Vb = V + (size_t)b * 49 * 512;
    float2 accA[TB];
#pragma unroll
    for (int tt = 0; tt < TB; tt++) accA[tt] = make_float2(0.0f, 0.0f);
#pragma unroll 7
    for (int k = 0; k < 49; k++) {
        float4 a4 = al4[k];
        float2 v = *(const float2*)(Vb + (size_t)k * 512 + tid * 2);
        accA[0].x = fmaf(a4.x, v.x, accA[0].x);  accA[0].y = fmaf(a4.x, v.y, accA[0].y);
        accA[1].x = fmaf(a4.y, v.x, accA[1].x);  accA[1].y = fmaf(a4.y, v.y, accA[1].y);
        accA[2].x = fmaf(a4.z, v.x, accA[2].x);  accA[2].y = fmaf(a4.z, v.y, accA[2].y);
        accA[3].x = fmaf(a4.w, v.x, accA[3].x);  accA[3].y = fmaf(a4.w, v.y, accA[3].y);
    }
#pragma unroll
    for (int tt = 0; tt < TB; tt++) {
        float beta = bl[tt];
        float2 sp = *(const float2*)(s_t + (size_t)(bt0 + tt) * 512 + tid * 2);
        float2 o;
        o.x = beta * sp.x + (1.0f - beta) * accA[tt].x;
        o.y = beta * sp.y + (1.0f - beta) * accA[tt].y;
        *(float2*)(out + (size_t)(bt0 + tt) * 512 + tid * 2) = o;
    }
}

// ---------------- launch ----------------
extern "C" void kernel_launch(void* const* d_in, const int* in_sizes, int n_in,
                              void* d_out, int out_size, void* d_ws, size_t ws_size,
                              hipStream_t stream) {
    const float* V   = (const float*)d_in[0];
    const float* h_t = (const float*)d_in[1];
    const float* s_t = (const float*)d_in[2];
    const float* Wv  = (const float*)d_in[3];
    const float* bv  = (const float*)d_in[4];
    const float* Wg  = (const float*)d_in[5];
    const float* bg  = (const float*)d_in[6];
    const float* Ws  = (const float*)d_in[7];
    const float* bs  = (const float*)d_in[8];
    const float* Wh  = (const float*)d_in[9];
    const float* bh  = (const float*)d_in[10];
    float* out = (float*)d_out;

    char* ws = (char*)d_ws;
    _Float16* Af16 = (_Float16*)(ws);                 // 9088*512*2  = 9,306,112
    _Float16* Wt   = (_Float16*)(ws + 9306112);       // 3*512*512*2 = 1,572,864
    float* ecv = (float*)(ws + 10878976);             // 896*512*4   = 1,835,008
    float* ecg = (float*)(ws + 12713984);             // 4096*512*4  = 8,388,608
    float* ecs = (float*)(ws + 21102592);             // 4096*512*4  = 8,388,608

    conv_all<<<3040, 256, 0, stream>>>(V, h_t, s_t, Wv, Wg, Ws, Af16, Wt);
    gemm_f16<<<284, 256, 0, stream>>>(Af16, Wt, bv, bg, bs, ecv, ecg, ecs);
    z_kernel<<<1024, 256, 0, stream>>>(ecv, ecg, ecs, V, s_t, Wh, bh, out);
}

// Round 7
// 126.583 us; speedup vs baseline: 1.0759x; 1.0759x over previous
//
#include <hip/hip_runtime.h>
#include <hip/hip_fp16.h>
#include <cstdint>
#include <cstddef>

// Problem constants
#define B_ 16
#define K_ 49
#define T_ 256
#define H_ 512
#define D_ 512

// tanh(x) = 1 - 2/(1 + e^{2x}) = 1 - 2*rcp(1 + 2^{x*2*log2e})
// TANH_SCALE folded into Wv/Wg/Ws (+biases); gemm epilogue stores 2^(scaled dot),
// so z_kernel's inner loop is pure fma/rcp (zero transcendentals).
#define TANH_SCALE 2.8853900817779268f
#define LOG2E 1.4426950408889634f

typedef _Float16 half8 __attribute__((ext_vector_type(8)));
typedef float floatx4 __attribute__((ext_vector_type(4)));

// ---------------- FRAGMENT-ORDER GLOBAL LAYOUT (round-7 change) ----------------
// Rounds 0-6 post-mortem: every gemm schedule (8-step drain, 3-buf counted vmcnt,
// BK=128 4-slot) landed at 25-28 us. The invariant was the STAGING ACCESS PATTERN:
// fragment-order LDS built from row-major global => each global_load_lds wave-instr
// read 64 scattered 16B segments (rows 1KB apart) => ~8x the L2 request count of a
// contiguous DMA; the gemm was L2-request-rate-bound, not schedule-bound.
// Fix: conv_all emits Af16/Wt PRE-SWIZZLED into fragment order, so every gemm DMA
// instruction reads 1KB CONTIGUOUS global -> linear LDS (m97/m173 pattern).
//
// A' layout: tile t (128 rows), slab kk (32 k), chunk c (0..511), elem e (0..7):
//   elem addr = t*65536 + kk*4096 + c*8 + e
//   with c = x8*64 + q*16 + f  <->  row = t*128 + x8*16 + f ; col = kk*32 + q*8 + e
// Row tiles: [0,6]=V(+pad), [7,38]=h_t, [39,70]=s_t  (896=7*128, 4992=39*128)
// B' (Wt) layout per problem p: addr = p*262144 + nt*65536 + kk*4096 + c*8 + e
//   with n = nt*128 + x8*16 + f ; k = kk*32 + q*8 + e
#define ROWS_A 9088
#define OFF_V 0
#define OFF_H 896
#define OFF_S 4992

__device__ __forceinline__ void async16(const _Float16* g, const _Float16* l) {
    // width=16 global->LDS DMA; LDS dest = wave-uniform base + lane*16
    __builtin_amdgcn_global_load_lds(
        (const __attribute__((address_space(1))) unsigned int*)g,
        (__attribute__((address_space(3))) unsigned int*)l, 16, 0, 0);
}

// ---------------- merged conversion kernel (now writes fragment order) ----------------
__global__ __launch_bounds__(256) void conv_all(const float* __restrict__ V,
                                                const float* __restrict__ h_t,
                                                const float* __restrict__ s_t,
                                                const float* __restrict__ Wv,
                                                const float* __restrict__ Wg,
                                                const float* __restrict__ Ws,
                                                _Float16* __restrict__ Af16,
                                                _Float16* __restrict__ Wt) {
    __shared__ float tile[32][33];
    int tid = threadIdx.x;
    if (blockIdx.x < 2272) {
        int idx = (blockIdx.x * 256 + tid) * 8;
        int row = idx >> 9;
        int col = idx & 511;
        const float* src;
        if (row < 784)        src = V   + (size_t)row * 512 + col;
        else if (row < 896)   src = nullptr;
        else if (row < 4992)  src = h_t + (size_t)(row - 896) * 512 + col;
        else                  src = s_t + (size_t)(row - 4992) * 512 + col;
        half8 h;
        if (src) {
            float4 f0 = *(const float4*)(src);
            float4 f1 = *(const float4*)(src + 4);
            h[0] = (_Float16)f0.x; h[1] = (_Float16)f0.y;
            h[2] = (_Float16)f0.z; h[3] = (_Float16)f0.w;
            h[4] = (_Float16)f1.x; h[5] = (_Float16)f1.y;
            h[6] = (_Float16)f1.z; h[7] = (_Float16)f1.w;
        } else {
            h = (half8)((_Float16)0.0f);
        }
        // fragment-order address: row -> (t,x8,f), col -> (kk,q)
        int t  = row >> 7, x8 = (row >> 4) & 7, f = row & 15;
        int kk = col >> 5, q  = (col >> 3) & 3;
        size_t off = (size_t)t * 65536 + (size_t)kk * 4096 + (size_t)(x8 * 64 + q * 16 + f) * 8;
        *(half8*)(Af16 + off) = h;
    } else {
        int bid = blockIdx.x - 2272;
        int p = bid >> 8;
        int rem = bid & 255;
        int bx = rem & 15, by = rem >> 4;
        const float* W = (p == 0) ? Wv : (p == 1) ? Wg : Ws;
        int tx = tid & 31, ty = tid >> 5;
        int c = bx * 32 + tx;
        int rbase = by * 32;
#pragma unroll
        for (int i = 0; i < 4; i++)
            tile[ty + i * 8][tx] = W[(size_t)(rbase + ty + i * 8) * 512 + c];
        __syncthreads();
        int k = rbase + tx;                      // B-operand col (k)
        int kk = k >> 5, q = (k >> 3) & 3, e = k & 7;
#pragma unroll
        for (int i = 0; i < 4; i++) {
            int n = bx * 32 + ty + i * 8;        // B-operand row (output col)
            int nt = n >> 7, x8 = (n >> 4) & 7, f = n & 15;
            size_t off = (size_t)p * 262144 + (size_t)nt * 65536 + (size_t)kk * 4096
                       + (size_t)(x8 * 64 + q * 16 + f) * 8 + e;
            Wt[off] = (_Float16)(tile[tx][ty + i * 8] * TANH_SCALE);
        }
    }
}

// ---------------- 3-problem fp16 MFMA GEMM, 128x128 tiles, BK=32, 3-buffer ----------------
// C = 2^(A @ W^T + bias)  (exp2 applied in epilogue: z_kernel consumes only 2^x).
// R5's verified schedule (3 LDS buffers, counted vmcnt(4), stage kk+2 after barrier
// kk, never drain to 0 in-loop) kept bit-for-bit; ONLY the staging addresses change:
// fragment-order global => gA/gB are lane-contiguous (each wave DMA instr = 1KB
// contiguous global, 8 full L2 lines). LDS layout/read offsets/MFMA/epilogue
// identical to the verified R5 kernel.
// XCD swizzle, bijective over 284 = 4*36 + 4*35 (ERRATA #11 form).
__global__ __launch_bounds__(256) void gemm_f16(
    const _Float16* __restrict__ Af16, const _Float16* __restrict__ Wt,
    const float* __restrict__ bv, const float* __restrict__ bg2,
    const float* __restrict__ bs, float* __restrict__ cv,
    float* __restrict__ cg, float* __restrict__ cs) {
    __shared__ __align__(16) _Float16 As[3][128 * 32];   // 3 x 8 KB
    __shared__ __align__(16) _Float16 Bs[3][128 * 32];   // 3 x 8 KB  (48 KB total)

    int bid = blockIdx.x;
    int jj = bid >> 3, xcd = bid & 7;
    int id = (xcd < 4) ? xcd * 36 + jj : 144 + (xcd - 4) * 35 + jj;   // bijective 284

    int rowbase; const _Float16* Bt; const float* bias; float* C;
    if (id < 28)        {            rowbase = OFF_V; Bt = Wt;          bias = bv;  C = cv; }
    else if (id < 156)  { id -= 28;  rowbase = OFF_H; Bt = Wt + 262144; bias = bg2; C = cg; }
    else                { id -= 156; rowbase = OFF_S; Bt = Wt + 524288; bias = bs;  C = cs; }
    int mrel = (id >> 2) * 128;          // output row base within this problem
    int tA   = (rowbase + mrel) >> 7;    // A' tile index (rowbase is 128-aligned)
    int nt   = id & 3;                   // B' tile index
    int n0   = nt * 128;                 // output col base

    int tid = threadIdx.x;
    int wave = tid >> 6, lane = tid & 63;
    int wr = wave >> 1, wc = wave & 1;   // 2x2 wave grid, each wave 64x64 out

    // staging: chunk c = i*256 + tid; global addr = tileBase + kk*4096 + c*8
    // => lane-contiguous (16B/lane), LDS dest linear at c*8 (fragment order)
    const _Float16* gA[2]; const _Float16* gB[2]; int ldsOff[2];
#pragma unroll
    for (int i = 0; i < 2; i++) {
        int c = i * 256 + tid;
        gA[i] = Af16 + (size_t)tA * 65536 + (size_t)c * 8;
        gB[i] = Bt   + (size_t)nt * 65536 + (size_t)c * 8;
        ldsOff[i] = c * 8;
    }

    floatx4 acc[4][4];
#pragma unroll
    for (int x = 0; x < 4; x++)
#pragma unroll
        for (int y = 0; y < 4; y++) acc[x][y] = (floatx4)0.0f;

    // prologue: stage K-steps 0,1 into buffers 0,1 (8 loads in flight per thread)
#pragma unroll
    for (int i = 0; i < 2; i++) async16(gA[i], &As[0][ldsOff[i]]);
#pragma unroll
    for (int i = 0; i < 2; i++) async16(gB[i], &Bs[0][ldsOff[i]]);
#pragma unroll
    for (int i = 0; i < 2; i++) async16(gA[i] + 4096, &As[1][ldsOff[i]]);
#pragma unroll
    for (int i = 0; i < 2; i++) async16(gB[i] + 4096, &Bs[1][ldsOff[i]]);

#pragma unroll
    for (int kk = 0; kk < 16; kk++) {
        const int cur = kk % 3;
        if (kk < 15) {
            asm volatile("s_waitcnt vmcnt(4)" ::: "memory");   // stage(kk) landed
        } else {
            asm volatile("s_waitcnt vmcnt(0)" ::: "memory");   // last step: drain
        }
        __builtin_amdgcn_s_barrier();
        __builtin_amdgcn_sched_barrier(0);

        if (kk < 14) {
            const int nb = (kk + 2) % 3;
#pragma unroll
            for (int i = 0; i < 2; i++) async16(gA[i] + (kk + 2) * 4096, &As[nb][ldsOff[i]]);
#pragma unroll
            for (int i = 0; i < 2; i++) async16(gB[i] + (kk + 2) * 4096, &Bs[nb][ldsOff[i]]);
        }

        half8 a[4], b[4];
#pragma unroll
        for (int t = 0; t < 4; t++) {
            a[t] = *(const half8*)&As[cur][((wr * 4 + t) * 64 + lane) * 8];
            b[t] = *(const half8*)&Bs[cur][((wc * 4 + t) * 64 + lane) * 8];
        }
#pragma unroll
        for (int x = 0; x < 4; x++)
#pragma unroll
            for (int y = 0; y < 4; y++)
                acc[x][y] = __builtin_amdgcn_mfma_f32_16x16x32_f16(a[x], b[y], acc[x][y], 0, 0, 0);
    }

    // epilogue: C/D layout col=lane&15, row=(lane>>4)*4+reg ; store 2^(dot+bias)
    int dn = lane & 15, dq = lane >> 4;
#pragma unroll
    for (int y = 0; y < 4; y++) {
        int colg = n0 + wc * 64 + y * 16 + dn;
        float bc = bias[colg] * TANH_SCALE;
#pragma unroll
        for (int x = 0; x < 4; x++) {
            int rowg = mrel + wr * 64 + x * 16 + dq * 4;
#pragma unroll
            for (int r = 0; r < 4; r++)
                C[(size_t)(rowg + r) * 512 + colg] = __builtin_amdgcn_exp2f(acc[x][y][r] + bc);
        }
    }
}

// ---------------- fused z / softmax / c_t / gate kernel ----------------
__device__ __forceinline__ float wave_sum(float v) {
#pragma unroll
    for (int o = 32; o > 0; o >>= 1) v += __shfl_xor(v, o);
    return v;
}
__device__ __forceinline__ float wave_max(float v) {
#pragma unroll
    for (int o = 32; o > 0; o >>= 1) v = fmaxf(v, __shfl_xor(v, o));
    return v;
}

// Sum 4 independent values across 64 lanes (group g=lane>>4 holds acc_g's total).
__device__ __forceinline__ float xsum4(float a0, float a1, float a2, float a3, int lane) {
    bool hi = (lane & 32) != 0;
    float t0 = hi ? a0 : a2;
    float t1 = hi ? a1 : a3;
    t0 = __shfl_xor(t0, 32);
    t1 = __shfl_xor(t1, 32);
    if (hi) { a0 = t0; a1 = t1; } else { a2 = t0; a3 = t1; }
    bool h2 = (lane & 16) != 0;
    float u0 = h2 ? a0 : a1;
    float u1 = h2 ? a2 : a3;
    u0 = __shfl_xor(u0, 16);
    u1 = __shfl_xor(u1, 16);
    if (h2) { a0 = u0; a2 = u1; } else { a1 = u0; a3 = u1; }
    float s = (a0 + a1) + (a2 + a3);
#pragma unroll
    for (int o = 8; o > 0; o >>= 1) s += __shfl_xor(s, o);
    return s;
}

// ecv/ecg/ecs hold 2^(scaled dot): e = ecv*ecg, tanh-dot = zbase - 2*sum(Wh*rcp(1+e))
#define TB 4
__global__ __launch_bounds__(256) void z_kernel(
    const float* __restrict__ ecv, const float* __restrict__ ecg,
    const float* __restrict__ ecs, const float* __restrict__ V,
    const float* __restrict__ s_t, const float* __restrict__ Wh,
    const float* __restrict__ bh, float* __restrict__ out) {
    int bx = blockIdx.x;           // 1024 blocks: b*64 + tgroup
    int b  = bx >> 6;
    int t0 = (bx & 63) << 2;
    int bt0 = b * 256 + t0;
    int tid = threadIdx.x;
    int wave = tid >> 6, lane = tid & 63;

    __shared__ float zl[TB][64];
    __shared__ float4 al4[52];
    __shared__ float bl[TB];

    // register-resident Wh and egv = 2^cg (d = j*64 + lane fixed per lane)
    float whv[8], egv[TB][8];
#pragma unroll
    for (int j = 0; j < 8; j++) whv[j] = Wh[j * 64 + lane];
#pragma unroll
    for (int tt = 0; tt < TB; tt++) {
        const float* cgp = ecg + (size_t)(bt0 + tt) * 512;
#pragma unroll
        for (int j = 0; j < 8; j++) egv[tt][j] = cgp[j * 64 + lane];
    }
    float s8 = 0.0f;
#pragma unroll
    for (int j = 0; j < 8; j++) s8 += whv[j];
    float zbase = wave_sum(s8) + bh[0];   // sum(Wh)+bh: tanh = 1-2r folded

    // 49 content tasks round-robin over 4 waves, software-prefetched
    float rv[8], rn[8];
    {
        const float* rp = ecv + (size_t)(b * 49 + wave) * 512;
#pragma unroll
        for (int j = 0; j < 8; j++) rv[j] = rp[j * 64 + lane];
    }
    for (int task = wave; task < 49; task += 4) {
        int nt = task + 4;
        if (nt < 49) {
            const float* rp = ecv + (size_t)(b * 49 + nt) * 512;
#pragma unroll
            for (int j = 0; j < 8; j++) rn[j] = rp[j * 64 + lane];
        }
        float acc[TB] = {0.0f, 0.0f, 0.0f, 0.0f};
#pragma unroll
        for (int tt = 0; tt < TB; tt++) {
#pragma unroll
            for (int j = 0; j < 8; j++) {
                float t = fmaf(rv[j], egv[tt][j], 1.0f);       // 1 + 2^(cv+cg)
                float r = __builtin_amdgcn_rcpf(t);            // v_rcp_f32
                acc[tt] = fmaf(whv[j], r, acc[tt]);
            }
        }
        float z = xsum4(acc[0], acc[1], acc[2], acc[3], lane);
        if ((lane & 15) == 0) zl[lane >> 4][task] = zbase - 2.0f * z;
#pragma unroll
        for (int j = 0; j < 8; j++) rv[j] = rn[j];
    }
    // ext task: wave tt handles t0+tt (reuses egv[tt])
#pragma unroll
    for (int tt = 0; tt < TB; tt++) {
        if (wave == tt) {
            const float* rp = ecs + (size_t)(bt0 + tt) * 512;
            float acc = 0.0f;
#pragma unroll
            for (int j = 0; j < 8; j++) {
                float t = fmaf(rp[j * 64 + lane], egv[tt][j], 1.0f);
                float r = __builtin_amdgcn_rcpf(t);
                acc = fmaf(whv[j], r, acc);
            }
            float s = wave_sum(acc);
            if (lane == 0) zl[tt][49] = zbase - 2.0f * s;
        }
    }
    __syncthreads();

    // 4 softmaxes in parallel: wave w handles tt=w
    {
        int w = wave;
        float z = (lane < 49) ? zl[w][lane] : -3.0e38f;
        float m = wave_max(z);
        float e = (lane < 49) ? __builtin_amdgcn_exp2f((z - m) * LOG2E) : 0.0f;
        float s = wave_sum(e);
        float zext = zl[w][49];
        float m2 = fmaxf(m, zext);
        float sc   = __builtin_amdgcn_exp2f((m - m2) * LOG2E);
        float eext = __builtin_amdgcn_exp2f((zext - m2) * LOG2E);
        float s2 = s * sc + eext;
        float beta = eext / s2;
        if (lane < 49) {
            float a = e / s;
            ((float*)&al4[lane])[w] = a;
            out[(size_t)B_ * T_ * H_ + (size_t)(bt0 + w) * 49 + lane] = a;   // alpha_t
        }
        if (lane == 0) {
            bl[w] = beta;
            out[(size_t)B_ * T_ * H_ + (size_t)B_ * T_ * K_ + (bt0 + w)] = beta;  // beta_t
        }
    }
    __syncthreads();

    // c_t + gate: float2 per lane, V read once per block
    const float* Vb = V + (size_t)b * 49 * 512;
    float2 accA[TB];
#pragma unroll
    for (int tt = 0; tt < TB; tt++) accA[tt] = make_float2(0.0f, 0.0f);
#pragma unroll 7
    for (int k = 0; k < 49; k++) {
        float4 a4 = al4[k];
        float2 v = *(const float2*)(Vb + (size_t)k * 512 + tid * 2);
        accA[0].x = fmaf(a4.x, v.x, accA[0].x);  accA[0].y = fmaf(a4.x, v.y, accA[0].y);
        accA[1].x = fmaf(a4.y, v.x, accA[1].x);  accA[1].y = fmaf(a4.y, v.y, accA[1].y);
        accA[2].x = fmaf(a4.z, v.x, accA[2].x);  accA[2].y = fmaf(a4.z, v.y, accA[2].y);
        accA[3].x = fmaf(a4.w, v.x, accA[3].x);  accA[3].y = fmaf(a4.w, v.y, accA[3].y);
    }
#pragma unroll
    for (int tt = 0; tt < TB; tt++) {
        float beta = bl[tt];
        float2 sp = *(const float2*)(s_t + (size_t)(bt0 + tt) * 512 + tid * 2);
        float2 o;
        o.x = beta * sp.x + (1.0f - beta) * accA[tt].x;
        o.y = beta * sp.y + (1.0f - beta) * accA[tt].y;
        *(float2*)(out + (size_t)(bt0 + tt) * 512 + tid * 2) = o;
    }
}

// ---------------- launch ----------------
extern "C" void kernel_launch(void* const* d_in, const int* in_sizes, int n_in,
                              void* d_out, int out_size, void* d_ws, size_t ws_size,
                              hipStream_t stream) {
    const float* V   = (const float*)d_in[0];
    const float* h_t = (const float*)d_in[1];
    const float* s_t = (const float*)d_in[2];
    const float* Wv  = (const float*)d_in[3];
    const float* bv  = (const float*)d_in[4];
    const float* Wg  = (const float*)d_in[5];
    const float* bg  = (const float*)d_in[6];
    const float* Ws  = (const float*)d_in[7];
    const float* bs  = (const float*)d_in[8];
    const float* Wh  = (const float*)d_in[9];
    const float* bh  = (const float*)d_in[10];
    float* out = (float*)d_out;

    char* ws = (char*)d_ws;
    _Float16* Af16 = (_Float16*)(ws);                 // 71 tiles * 65536 * 2 = 9,306,112
    _Float16* Wt   = (_Float16*)(ws + 9306112);       // 3*512*512*2 = 1,572,864
    float* ecv = (float*)(ws + 10878976);             // 896*512*4   = 1,835,008
    float* ecg = (float*)(ws + 12713984);             // 4096*512*4  = 8,388,608
    float* ecs = (float*)(ws + 21102592);             // 4096*512*4  = 8,388,608

    conv_all<<<3040, 256, 0, stream>>>(V, h_t, s_t, Wv, Wg, Ws, Af16, Wt);
    gemm_f16<<<284, 256, 0, stream>>>(Af16, Wt, bv, bg, bs, ecv, ecg, ecs);
    z_kernel<<<1024, 256, 0, stream>>>(ecv, ecg, ecs, V, s_t, Wh, bh, out);
}